// Round 3
// baseline (412.797 us; speedup 1.0000x reference)
//
#include <hip/hip_runtime.h>
#include <hip/hip_bf16.h>
#include <cstdint>
#include <cstddef>

typedef __bf16 bf16;
typedef __attribute__((ext_vector_type(8))) __bf16 bf16x8;
typedef __attribute__((ext_vector_type(4))) float floatx4;

#define NPIX 65536   // B*H*W

// ---------------------------------------------------------------- K-1: fp32 x -> bf16 copy
__global__ void k_convert(const float* __restrict__ xf, bf16* __restrict__ xb) {
    size_t i = ((size_t)blockIdx.x * 256 + threadIdx.x) * 8;
    float4 a = *(const float4*)(xf + i);
    float4 b = *(const float4*)(xf + i + 4);
    bf16x8 v;
    v[0] = (bf16)a.x; v[1] = (bf16)a.y; v[2] = (bf16)a.z; v[3] = (bf16)a.w;
    v[4] = (bf16)b.x; v[5] = (bf16)b.y; v[6] = (bf16)b.z; v[7] = (bf16)b.w;
    *(bf16x8*)(xb + i) = v;
}

// ---------------------------------------------------------------- K0: Wfull = [Wo | Wo@Wc] (bf16), bco = Wo@bc + bo (fp32)
__global__ void k_prep_w(const float* __restrict__ Wc, const float* __restrict__ bc,
                         const float* __restrict__ Wo, const float* __restrict__ bo,
                         bf16* __restrict__ Wfull, float* __restrict__ bco) {
    int blk = blockIdx.x;
    int t = threadIdx.x;          // 0..383
    if (blk < 384) {
        int o = blk;
        float acc = 0.f;
        for (int d = 0; d < 384; ++d)
            acc += Wo[o * 384 + d] * Wc[d * 384 + t];
        Wfull[(size_t)o * 768 + t]       = (bf16)Wo[o * 384 + t];
        Wfull[(size_t)o * 768 + 384 + t] = (bf16)acc;
    } else {
        int o = t;
        float acc = bo[o];
        for (int d = 0; d < 384; ++d)
            acc += Wo[o * 384 + d] * bc[d];
        bco[o] = acc;
    }
}

// ---------------------------------------------------------------- K1: projections (E=2), x in bf16, W1 in fp32
// yh[b][e][h][w], yw[b][e][w][h]  (fp32)
__global__ void k_proj(const bf16* __restrict__ x,
                       const float* __restrict__ W1h, const float* __restrict__ b1h,
                       const float* __restrict__ W1w, const float* __restrict__ b1w,
                       float* __restrict__ yh, float* __restrict__ yw) {
    int t  = threadIdx.x;
    int lg = t & 7;                 // lane within 8-lane pixel group
    int pg = t >> 3;                // pixel group in block (0..31)
    int p  = blockIdx.x * 32 + pg;  // pixel id
    int b = p >> 10, h = (p >> 5) & 31, w = p & 31;
    const bf16x8* xp = (const bf16x8*)(x + (size_t)p * 384);
    float a0 = 0.f, a1 = 0.f, a2 = 0.f, a3 = 0.f;
#pragma unroll
    for (int j = 0; j < 6; ++j) {
        int c = j * 8 + lg;         // 8-element chunk 0..47
        bf16x8 xv = xp[c];
        const float4* h0 = (const float4*)(W1h + c * 8);
        const float4* h1 = (const float4*)(W1h + 384 + c * 8);
        const float4* w0 = (const float4*)(W1w + c * 8);
        const float4* w1 = (const float4*)(W1w + 384 + c * 8);
        float4 h0a = h0[0], h0b = h0[1], h1a = h1[0], h1b = h1[1];
        float4 w0a = w0[0], w0b = w0[1], w1a = w1[0], w1b = w1[1];
        float xf[8];
#pragma unroll
        for (int i = 0; i < 8; ++i) xf[i] = (float)xv[i];
        a0 += xf[0]*h0a.x + xf[1]*h0a.y + xf[2]*h0a.z + xf[3]*h0a.w
            + xf[4]*h0b.x + xf[5]*h0b.y + xf[6]*h0b.z + xf[7]*h0b.w;
        a1 += xf[0]*h1a.x + xf[1]*h1a.y + xf[2]*h1a.z + xf[3]*h1a.w
            + xf[4]*h1b.x + xf[5]*h1b.y + xf[6]*h1b.z + xf[7]*h1b.w;
        a2 += xf[0]*w0a.x + xf[1]*w0a.y + xf[2]*w0a.z + xf[3]*w0a.w
            + xf[4]*w0b.x + xf[5]*w0b.y + xf[6]*w0b.z + xf[7]*w0b.w;
        a3 += xf[0]*w1a.x + xf[1]*w1a.y + xf[2]*w1a.z + xf[3]*w1a.w
            + xf[4]*w1b.x + xf[5]*w1b.y + xf[6]*w1b.z + xf[7]*w1b.w;
    }
#pragma unroll
    for (int m = 1; m < 8; m <<= 1) {
        a0 += __shfl_xor(a0, m, 64);
        a1 += __shfl_xor(a1, m, 64);
        a2 += __shfl_xor(a2, m, 64);
        a3 += __shfl_xor(a3, m, 64);
    }
    if (lg == 0) {
        yh[((b * 2 + 0) * 32 + h) * 32 + w] = a0 + b1h[0];
        yh[((b * 2 + 1) * 32 + h) * 32 + w] = a1 + b1h[1];
        yw[((b * 2 + 0) * 32 + w) * 32 + h] = a2 + b1w[0];
        yw[((b * 2 + 1) * 32 + w) * 32 + h] = a3 + b1w[1];
    }
}

// ---------------------------------------------------------------- K2: grouped mix + softmax -> attn[b][l][r1][r2] (bf16)
// yproj: [B][2][32][32] (= [b][e][r][l]); W2: fp32 [1024][8]; b2: fp32 [1024]
__global__ void k_attn(const float* __restrict__ yproj,
                       const float* __restrict__ W2, const float* __restrict__ b2,
                       bf16* __restrict__ attn) {
    int blk = blockIdx.x;                 // B*32
    int bi = blk >> 5, r1 = blk & 31;
    int g = r1 >> 2;
    int cb = g * 8;
    int e = cb >> 5, rb = cb & 31;        // 8 consecutive rows of plane e
    int lane = threadIdx.x;               // 64
    int l = lane & 31, half = lane >> 5;
    float yv[8];
    const float* ybase = yproj + (((bi * 2 + e) * 32 + rb) * 32 + l);
#pragma unroll
    for (int c = 0; c < 8; ++c) yv[c] = ybase[c * 32];
    float z[16];
#pragma unroll
    for (int jj = 0; jj < 16; ++jj) {
        int r2 = half * 16 + jj;
        int row = r1 * 32 + r2;
        const float4* wp = (const float4*)(W2 + (size_t)row * 8);
        float4 wa = wp[0], wb = wp[1];
        z[jj] = b2[row]
              + yv[0]*wa.x + yv[1]*wa.y + yv[2]*wa.z + yv[3]*wa.w
              + yv[4]*wb.x + yv[5]*wb.y + yv[6]*wb.z + yv[7]*wb.w;
    }
    float m = -1e30f;
#pragma unroll
    for (int jj = 0; jj < 16; ++jj) m = fmaxf(m, z[jj]);
    m = fmaxf(m, __shfl_xor(m, 32, 64));
    float s = 0.f;
#pragma unroll
    for (int jj = 0; jj < 16; ++jj) { z[jj] = __expf(z[jj] - m); s += z[jj]; }
    s += __shfl_xor(s, 32, 64);
    float inv = 1.f / s;
    bf16x8 o0, o1;
#pragma unroll
    for (int jj = 0; jj < 8; ++jj) o0[jj] = (bf16)(z[jj] * inv);
#pragma unroll
    for (int jj = 0; jj < 8; ++jj) o1[jj] = (bf16)(z[8 + jj] * inv);
    bf16x8* dst = (bf16x8*)(attn + ((((size_t)bi * 32 + l) * 32 + r1) * 32 + half * 16));
    dst[0] = o0;
    dst[1] = o1;
}

// ---------------------------------------------------------------- K3: Yh apply (write T, bf16)
// T[b,h,w,d] = sum_j attn_h[b,w,h,j] * x[b,j,w,d]
__global__ void k_yh(const bf16* __restrict__ x, const bf16* __restrict__ attn_h,
                     bf16* __restrict__ T) {
    int blk = blockIdx.x;          // B*W
    int bi = blk >> 5, w = blk & 31;
    int tid = threadIdx.x;
    int wv = tid >> 6, lane = tid & 63;
    int n16 = lane & 15, quad = lane >> 4;
    const bf16* abase = attn_h + ((size_t)(bi * 32 + w) * 32) * 32;
    bf16x8 af0 = *(const bf16x8*)(abase + (n16) * 32 + quad * 8);
    bf16x8 af1 = *(const bf16x8*)(abase + (16 + n16) * 32 + quad * 8);
    for (int t6 = 0; t6 < 6; ++t6) {
        int nt = wv * 6 + t6;
        int dcol = nt * 16 + n16;
        bf16x8 bfrag;
#pragma unroll
        for (int i = 0; i < 8; ++i) {
            int j = quad * 8 + i;
            bfrag[i] = x[((size_t)(bi * 32 + j) * 32 + w) * 384 + dcol];
        }
        floatx4 c0 = {0.f, 0.f, 0.f, 0.f}, c1 = {0.f, 0.f, 0.f, 0.f};
        c0 = __builtin_amdgcn_mfma_f32_16x16x32_bf16(af0, bfrag, c0, 0, 0, 0);
        c1 = __builtin_amdgcn_mfma_f32_16x16x32_bf16(af1, bfrag, c1, 0, 0, 0);
#pragma unroll
        for (int r = 0; r < 4; ++r) {
            int h0 = quad * 4 + r;
            T[((size_t)(bi * 32 + h0) * 32 + w) * 384 + dcol]        = (bf16)c0[r];
            T[((size_t)(bi * 32 + (16 + h0)) * 32 + w) * 384 + dcol] = (bf16)c1[r];
        }
    }
}

// ---------------------------------------------------------------- K4: Yw apply (accumulate into T)
// T[b,h,w,d] += sum_j attn_w[b,h,w,j] * x[b,h,j,d]
__global__ void k_yw(const bf16* __restrict__ x, const bf16* __restrict__ attn_w,
                     bf16* __restrict__ T) {
    int blk = blockIdx.x;          // B*H
    int bi = blk >> 5, h = blk & 31;
    int tid = threadIdx.x;
    int wv = tid >> 6, lane = tid & 63;
    int n16 = lane & 15, quad = lane >> 4;
    const bf16* abase = attn_w + ((size_t)(bi * 32 + h) * 32) * 32;
    const bf16* xb = x + ((size_t)(bi * 32 + h) * 32) * 384;
    bf16* Tb = T + ((size_t)(bi * 32 + h) * 32) * 384;
    bf16x8 af0 = *(const bf16x8*)(abase + (n16) * 32 + quad * 8);
    bf16x8 af1 = *(const bf16x8*)(abase + (16 + n16) * 32 + quad * 8);
    for (int t6 = 0; t6 < 6; ++t6) {
        int nt = wv * 6 + t6;
        int dcol = nt * 16 + n16;
        bf16x8 bfrag;
#pragma unroll
        for (int i = 0; i < 8; ++i) {
            int j = quad * 8 + i;
            bfrag[i] = xb[(size_t)j * 384 + dcol];
        }
        floatx4 c0 = {0.f, 0.f, 0.f, 0.f}, c1 = {0.f, 0.f, 0.f, 0.f};
        c0 = __builtin_amdgcn_mfma_f32_16x16x32_bf16(af0, bfrag, c0, 0, 0, 0);
        c1 = __builtin_amdgcn_mfma_f32_16x16x32_bf16(af1, bfrag, c1, 0, 0, 0);
#pragma unroll
        for (int r = 0; r < 4; ++r) {
            int w0 = quad * 4 + r;
            size_t o0 = (size_t)w0 * 384 + dcol;
            size_t o1 = (size_t)(16 + w0) * 384 + dcol;
            Tb[o0] = (bf16)((float)Tb[o0] + c0[r]);
            Tb[o1] = (bf16)((float)Tb[o1] + c1[r]);
        }
    }
}

// ---------------------------------------------------------------- K5: out = [T|xb] @ Wfull^T + bco   (M=65536,N=384,K=768), out fp32
__global__ __launch_bounds__(256) void k_gemm(const bf16* __restrict__ T, const bf16* __restrict__ x,
                                              const bf16* __restrict__ Wfull, const float* __restrict__ bco,
                                              float* __restrict__ out) {
    __shared__ bf16 As[128 * 64];
    __shared__ bf16 Bs[128 * 64];
    int obase = blockIdx.x * 128;   // 3 N-tiles adjacent for A-tile L2 reuse
    int pbase = blockIdx.y * 128;
    int tid = threadIdx.x;
    int wv = tid >> 6, lane = tid & 63;
    int wm = wv & 1, wn = wv >> 1;
    int n16 = lane & 15, quad = lane >> 4;
    int lrow = tid >> 3;           // 0..31
    int lchunk = tid & 7;          // 0..7
    floatx4 zero = {0.f, 0.f, 0.f, 0.f};
    floatx4 acc[4][4];
#pragma unroll
    for (int i = 0; i < 4; ++i)
#pragma unroll
        for (int j = 0; j < 4; ++j) acc[i][j] = zero;

    for (int kt = 0; kt < 12; ++kt) {
        const bf16* Asrc = (kt < 6) ? (T + (size_t)pbase * 384 + kt * 64)
                                    : (x + (size_t)pbase * 384 + (kt - 6) * 64);
        const bf16* Bsrc = Wfull + (size_t)obase * 768 + kt * 64;
        bf16x8 av[4], bv[4];
#pragma unroll
        for (int s = 0; s < 4; ++s)
            av[s] = *(const bf16x8*)(Asrc + (size_t)(s * 32 + lrow) * 384 + lchunk * 8);
#pragma unroll
        for (int s = 0; s < 4; ++s)
            bv[s] = *(const bf16x8*)(Bsrc + (size_t)(s * 32 + lrow) * 768 + lchunk * 8);
        __syncthreads();           // previous iteration's LDS reads done
#pragma unroll
        for (int s = 0; s < 4; ++s)
            *(bf16x8*)(As + (s * 32 + lrow) * 64 + lchunk * 8) = av[s];
#pragma unroll
        for (int s = 0; s < 4; ++s)
            *(bf16x8*)(Bs + (s * 32 + lrow) * 64 + lchunk * 8) = bv[s];
        __syncthreads();
#pragma unroll
        for (int ks = 0; ks < 2; ++ks) {
            bf16x8 a[4], b[4];
#pragma unroll
            for (int i = 0; i < 4; ++i)
                a[i] = *(const bf16x8*)(As + (wm * 64 + i * 16 + n16) * 64 + ks * 32 + quad * 8);
#pragma unroll
            for (int i = 0; i < 4; ++i)
                b[i] = *(const bf16x8*)(Bs + (wn * 64 + i * 16 + n16) * 64 + ks * 32 + quad * 8);
#pragma unroll
            for (int i = 0; i < 4; ++i)
#pragma unroll
                for (int j = 0; j < 4; ++j)
                    acc[i][j] = __builtin_amdgcn_mfma_f32_16x16x32_bf16(a[i], b[j], acc[i][j], 0, 0, 0);
        }
    }
    // epilogue: fp32 output
#pragma unroll
    for (int j = 0; j < 4; ++j) {
        int o = obase + wn * 64 + j * 16 + n16;
        float bcv = bco[o];
#pragma unroll
        for (int i = 0; i < 4; ++i) {
            int prow = pbase + wm * 64 + i * 16 + quad * 4;
#pragma unroll
            for (int r = 0; r < 4; ++r)
                out[(size_t)(prow + r) * 384 + o] = acc[i][j][r] + bcv;
        }
    }
}

// ---------------------------------------------------------------- launch
extern "C" void kernel_launch(void* const* d_in, const int* in_sizes, int n_in,
                              void* d_out, int out_size, void* d_ws, size_t ws_size,
                              hipStream_t stream) {
    const float* x   = (const float*)d_in[0];
    const float* Wc  = (const float*)d_in[1];
    const float* bc  = (const float*)d_in[2];
    const float* Wo  = (const float*)d_in[3];
    const float* bo  = (const float*)d_in[4];
    const float* W1h = (const float*)d_in[5];
    const float* b1h = (const float*)d_in[6];
    const float* W2h = (const float*)d_in[7];
    const float* b2h = (const float*)d_in[8];
    const float* W1w = (const float*)d_in[9];
    const float* b1w = (const float*)d_in[10];
    const float* W2w = (const float*)d_in[11];
    const float* b2w = (const float*)d_in[12];
    float* out = (float*)d_out;

    char* ws = (char*)d_ws;
    size_t off = 0;
    auto alloc = [&](size_t bytes) {
        void* p = ws + off;
        off = (off + bytes + 255) & ~(size_t)255;
        return p;
    };
    bf16*  xb     = (bf16*)alloc((size_t)NPIX * 384 * 2);  // bf16 copy of x
    float* yh     = (float*)alloc((size_t)131072 * 4);     // [B][2][32][32]
    float* yw     = (float*)alloc((size_t)131072 * 4);
    bf16*  attn_h = (bf16*)alloc((size_t)2097152 * 2);     // [B][W][H][H]
    bf16*  attn_w = (bf16*)alloc((size_t)2097152 * 2);     // [B][H][W][W]
    bf16*  T      = (bf16*)alloc((size_t)NPIX * 384 * 2);  // Yh+Yw
    bf16*  Wfull  = (bf16*)alloc((size_t)384 * 768 * 2);   // [Wo | Wo@Wc]
    float* bco    = (float*)alloc((size_t)384 * 4);

    hipLaunchKernelGGL(k_convert, dim3(12288), dim3(256), 0, stream, x, xb);
    hipLaunchKernelGGL(k_prep_w, dim3(385), dim3(384), 0, stream, Wc, bc, Wo, bo, Wfull, bco);
    hipLaunchKernelGGL(k_proj, dim3(2048), dim3(256), 0, stream, xb, W1h, b1h, W1w, b1w, yh, yw);
    hipLaunchKernelGGL(k_attn, dim3(2048), dim3(64), 0, stream, yh, W2h, b2h, attn_h);
    hipLaunchKernelGGL(k_attn, dim3(2048), dim3(64), 0, stream, yw, W2w, b2w, attn_w);
    hipLaunchKernelGGL(k_yh, dim3(2048), dim3(256), 0, stream, xb, attn_h, T);
    hipLaunchKernelGGL(k_yw, dim3(2048), dim3(256), 0, stream, xb, attn_w, T);
    hipLaunchKernelGGL(k_gemm, dim3(3, 512), dim3(256), 0, stream, T, xb, Wfull, bco, out);
}

// Round 4
// 372.568 us; speedup vs baseline: 1.1080x; 1.1080x over previous
//
#include <hip/hip_runtime.h>
#include <hip/hip_bf16.h>
#include <cstdint>
#include <cstddef>

typedef __bf16 bf16;
typedef __attribute__((ext_vector_type(8))) __bf16 bf16x8;
typedef __attribute__((ext_vector_type(4))) float floatx4;

#define NPIX 65536   // B*H*W

// ---------------------------------------------------------------- K0: Wfull = [Wo | Wo@Wc] (bf16), bco = Wo@bc + bo (fp32)
__global__ void k_prep_w(const float* __restrict__ Wc, const float* __restrict__ bc,
                         const float* __restrict__ Wo, const float* __restrict__ bo,
                         bf16* __restrict__ Wfull, float* __restrict__ bco) {
    int blk = blockIdx.x;
    int t = threadIdx.x;          // 0..383
    if (blk < 384) {
        int o = blk;
        float acc = 0.f;
        for (int d = 0; d < 384; ++d)
            acc += Wo[o * 384 + d] * Wc[d * 384 + t];
        Wfull[(size_t)o * 768 + t]       = (bf16)Wo[o * 384 + t];
        Wfull[(size_t)o * 768 + 384 + t] = (bf16)acc;
    } else {
        int o = t;
        float acc = bo[o];
        for (int d = 0; d < 384; ++d)
            acc += Wo[o * 384 + d] * bc[d];
        bco[o] = acc;
    }
}

// ---------------------------------------------------------------- K1: convert + projections (E=2)
// reads fp32 x, writes bf16 xb, computes yh[b][e][h][w], yw[b][e][w][h] (fp32)
__global__ void k_proj(const float* __restrict__ xf, bf16* __restrict__ xb,
                       const float* __restrict__ W1h, const float* __restrict__ b1h,
                       const float* __restrict__ W1w, const float* __restrict__ b1w,
                       float* __restrict__ yh, float* __restrict__ yw) {
    int t  = threadIdx.x;
    int lg = t & 7;                 // lane within 8-lane pixel group
    int pg = t >> 3;                // pixel group in block (0..31)
    int p  = blockIdx.x * 32 + pg;  // pixel id
    int b = p >> 10, h = (p >> 5) & 31, w = p & 31;
    const float4* xp4 = (const float4*)(xf + (size_t)p * 384);
    float a0 = 0.f, a1 = 0.f, a2 = 0.f, a3 = 0.f;
#pragma unroll
    for (int j = 0; j < 6; ++j) {
        int c = j * 8 + lg;         // 8-element chunk 0..47
        float4 xa = xp4[c * 2], xcv = xp4[c * 2 + 1];
        // convert + store bf16 copy
        bf16x8 v;
        v[0] = (bf16)xa.x; v[1] = (bf16)xa.y; v[2] = (bf16)xa.z; v[3] = (bf16)xa.w;
        v[4] = (bf16)xcv.x; v[5] = (bf16)xcv.y; v[6] = (bf16)xcv.z; v[7] = (bf16)xcv.w;
        *(bf16x8*)(xb + (size_t)p * 384 + c * 8) = v;
        const float4* h0 = (const float4*)(W1h + c * 8);
        const float4* h1 = (const float4*)(W1h + 384 + c * 8);
        const float4* w0 = (const float4*)(W1w + c * 8);
        const float4* w1 = (const float4*)(W1w + 384 + c * 8);
        float4 h0a = h0[0], h0b = h0[1], h1a = h1[0], h1b = h1[1];
        float4 w0a = w0[0], w0b = w0[1], w1a = w1[0], w1b = w1[1];
        a0 += xa.x*h0a.x + xa.y*h0a.y + xa.z*h0a.z + xa.w*h0a.w
            + xcv.x*h0b.x + xcv.y*h0b.y + xcv.z*h0b.z + xcv.w*h0b.w;
        a1 += xa.x*h1a.x + xa.y*h1a.y + xa.z*h1a.z + xa.w*h1a.w
            + xcv.x*h1b.x + xcv.y*h1b.y + xcv.z*h1b.z + xcv.w*h1b.w;
        a2 += xa.x*w0a.x + xa.y*w0a.y + xa.z*w0a.z + xa.w*w0a.w
            + xcv.x*w0b.x + xcv.y*w0b.y + xcv.z*w0b.z + xcv.w*w0b.w;
        a3 += xa.x*w1a.x + xa.y*w1a.y + xa.z*w1a.z + xa.w*w1a.w
            + xcv.x*w1b.x + xcv.y*w1b.y + xcv.z*w1b.z + xcv.w*w1b.w;
    }
#pragma unroll
    for (int m = 1; m < 8; m <<= 1) {
        a0 += __shfl_xor(a0, m, 64);
        a1 += __shfl_xor(a1, m, 64);
        a2 += __shfl_xor(a2, m, 64);
        a3 += __shfl_xor(a3, m, 64);
    }
    if (lg == 0) {
        yh[((b * 2 + 0) * 32 + h) * 32 + w] = a0 + b1h[0];
        yh[((b * 2 + 1) * 32 + h) * 32 + w] = a1 + b1h[1];
        yw[((b * 2 + 0) * 32 + w) * 32 + h] = a2 + b1w[0];
        yw[((b * 2 + 1) * 32 + w) * 32 + h] = a3 + b1w[1];
    }
}

// ---------------------------------------------------------------- K2: grouped mix + softmax -> attn[b][l][r1][r2] (bf16)
__global__ void k_attn(const float* __restrict__ yproj,
                       const float* __restrict__ W2, const float* __restrict__ b2,
                       bf16* __restrict__ attn) {
    int blk = blockIdx.x;                 // B*32
    int bi = blk >> 5, r1 = blk & 31;
    int g = r1 >> 2;
    int cb = g * 8;
    int e = cb >> 5, rb = cb & 31;        // 8 consecutive rows of plane e
    int lane = threadIdx.x;               // 64
    int l = lane & 31, half = lane >> 5;
    float yv[8];
    const float* ybase = yproj + (((bi * 2 + e) * 32 + rb) * 32 + l);
#pragma unroll
    for (int c = 0; c < 8; ++c) yv[c] = ybase[c * 32];
    float z[16];
#pragma unroll
    for (int jj = 0; jj < 16; ++jj) {
        int r2 = half * 16 + jj;
        int row = r1 * 32 + r2;
        const float4* wp = (const float4*)(W2 + (size_t)row * 8);
        float4 wa = wp[0], wb = wp[1];
        z[jj] = b2[row]
              + yv[0]*wa.x + yv[1]*wa.y + yv[2]*wa.z + yv[3]*wa.w
              + yv[4]*wb.x + yv[5]*wb.y + yv[6]*wb.z + yv[7]*wb.w;
    }
    float m = -1e30f;
#pragma unroll
    for (int jj = 0; jj < 16; ++jj) m = fmaxf(m, z[jj]);
    m = fmaxf(m, __shfl_xor(m, 32, 64));
    float s = 0.f;
#pragma unroll
    for (int jj = 0; jj < 16; ++jj) { z[jj] = __expf(z[jj] - m); s += z[jj]; }
    s += __shfl_xor(s, 32, 64);
    float inv = 1.f / s;
    bf16x8 o0, o1;
#pragma unroll
    for (int jj = 0; jj < 8; ++jj) o0[jj] = (bf16)(z[jj] * inv);
#pragma unroll
    for (int jj = 0; jj < 8; ++jj) o1[jj] = (bf16)(z[8 + jj] * inv);
    bf16x8* dst = (bf16x8*)(attn + ((((size_t)bi * 32 + l) * 32 + r1) * 32 + half * 16));
    dst[0] = o0;
    dst[1] = o1;
}

// ---------------------------------------------------------------- K3: fused Yh+Yw -> T (bf16), one block per (b, d-chunk16)
// phase1: Yh into fp32 LDS; phase2: Yw + LDS -> T (single write, no RMW)
__global__ __launch_bounds__(256) void k_mix(const bf16* __restrict__ x,
                                             const bf16* __restrict__ attn_h,
                                             const bf16* __restrict__ attn_w,
                                             bf16* __restrict__ T) {
    __shared__ float Ts[1024 * 16];     // [pixel = h*32+w][d16]  (64 KB)
    int c  = blockIdx.x;                // d-chunk 0..23
    int bi = blockIdx.y;                // image
    int dbase = c * 16;
    int tid = threadIdx.x;
    int wv = tid >> 6, lane = tid & 63;
    int n16 = lane & 15, quad = lane >> 4;
    int dcol = dbase + n16;

    // ---- phase 1: Yh[h,w,d] = sum_j ah[w,h,j] x[j,w,d] -> Ts
    for (int wl = 0; wl < 8; ++wl) {
        int w = wv * 8 + wl;
        const bf16* abase = attn_h + ((size_t)(bi * 32 + w) * 32) * 32;
        bf16x8 af0 = *(const bf16x8*)(abase + (n16) * 32 + quad * 8);
        bf16x8 af1 = *(const bf16x8*)(abase + (16 + n16) * 32 + quad * 8);
        bf16x8 bfrag;
#pragma unroll
        for (int i = 0; i < 8; ++i) {
            int j = quad * 8 + i;
            bfrag[i] = x[((size_t)(bi * 32 + j) * 32 + w) * 384 + dcol];
        }
        floatx4 c0 = {0.f, 0.f, 0.f, 0.f}, c1 = {0.f, 0.f, 0.f, 0.f};
        c0 = __builtin_amdgcn_mfma_f32_16x16x32_bf16(af0, bfrag, c0, 0, 0, 0);
        c1 = __builtin_amdgcn_mfma_f32_16x16x32_bf16(af1, bfrag, c1, 0, 0, 0);
#pragma unroll
        for (int r = 0; r < 4; ++r) {
            int h0 = quad * 4 + r;
            Ts[(h0 * 32 + w) * 16 + n16]        = c0[r];
            Ts[((16 + h0) * 32 + w) * 16 + n16] = c1[r];
        }
    }
    __syncthreads();
    // ---- phase 2: Yw[h,w,d] = sum_j aw[h,w,j] x[h,j,d]; T = Yh + Yw
    for (int hl = 0; hl < 8; ++hl) {
        int h = wv * 8 + hl;
        const bf16* abase = attn_w + ((size_t)(bi * 32 + h) * 32) * 32;
        const bf16* xr = x + ((size_t)(bi * 32 + h) * 32) * 384;
        bf16* Tr = T + ((size_t)(bi * 32 + h) * 32) * 384;
        bf16x8 af0 = *(const bf16x8*)(abase + (n16) * 32 + quad * 8);
        bf16x8 af1 = *(const bf16x8*)(abase + (16 + n16) * 32 + quad * 8);
        bf16x8 bfrag;
#pragma unroll
        for (int i = 0; i < 8; ++i) {
            int j = quad * 8 + i;
            bfrag[i] = xr[(size_t)j * 384 + dcol];
        }
        floatx4 c0 = {0.f, 0.f, 0.f, 0.f}, c1 = {0.f, 0.f, 0.f, 0.f};
        c0 = __builtin_amdgcn_mfma_f32_16x16x32_bf16(af0, bfrag, c0, 0, 0, 0);
        c1 = __builtin_amdgcn_mfma_f32_16x16x32_bf16(af1, bfrag, c1, 0, 0, 0);
#pragma unroll
        for (int r = 0; r < 4; ++r) {
            int w0 = quad * 4 + r;
            Tr[(size_t)w0 * 384 + dcol]        = (bf16)(c0[r] + Ts[(h * 32 + w0) * 16 + n16]);
            Tr[(size_t)(16 + w0) * 384 + dcol] = (bf16)(c1[r] + Ts[(h * 32 + (16 + w0)) * 16 + n16]);
        }
    }
}

// ---------------------------------------------------------------- K5: out = [T|xb] @ Wfull^T + bco   (M=65536,N=384,K=768), out fp32
// padded LDS (+8 elems/row) kills b128 bank conflicts; XCD-aware tile map
// keeps a pixel-tile's 3 N-tiles consecutive within one XCD L2.
#define LDP 72
__global__ __launch_bounds__(256) void k_gemm(const bf16* __restrict__ T, const bf16* __restrict__ x,
                                              const bf16* __restrict__ Wfull, const float* __restrict__ bco,
                                              float* __restrict__ out) {
    __shared__ bf16 As[128 * LDP];
    __shared__ bf16 Bs[128 * LDP];
    int bx = blockIdx.x;               // 0..1535
    int gid = (bx & 7) * 192 + (bx >> 3);
    int nt = gid % 3, pt = gid / 3;
    int obase = nt * 128;
    int pbase = pt * 128;
    int tid = threadIdx.x;
    int wv = tid >> 6, lane = tid & 63;
    int wm = wv & 1, wn = wv >> 1;
    int n16 = lane & 15, quad = lane >> 4;
    int lrow = tid >> 3;           // 0..31
    int lchunk = tid & 7;          // 0..7
    floatx4 zero = {0.f, 0.f, 0.f, 0.f};
    floatx4 acc[4][4];
#pragma unroll
    for (int i = 0; i < 4; ++i)
#pragma unroll
        for (int j = 0; j < 4; ++j) acc[i][j] = zero;

    for (int kt = 0; kt < 12; ++kt) {
        const bf16* Asrc = (kt < 6) ? (T + (size_t)pbase * 384 + kt * 64)
                                    : (x + (size_t)pbase * 384 + (kt - 6) * 64);
        const bf16* Bsrc = Wfull + (size_t)obase * 768 + kt * 64;
        bf16x8 av[4], bv[4];
#pragma unroll
        for (int s = 0; s < 4; ++s)
            av[s] = *(const bf16x8*)(Asrc + (size_t)(s * 32 + lrow) * 384 + lchunk * 8);
#pragma unroll
        for (int s = 0; s < 4; ++s)
            bv[s] = *(const bf16x8*)(Bsrc + (size_t)(s * 32 + lrow) * 768 + lchunk * 8);
        __syncthreads();           // previous iteration's LDS reads done
#pragma unroll
        for (int s = 0; s < 4; ++s)
            *(bf16x8*)(As + (s * 32 + lrow) * LDP + lchunk * 8) = av[s];
#pragma unroll
        for (int s = 0; s < 4; ++s)
            *(bf16x8*)(Bs + (s * 32 + lrow) * LDP + lchunk * 8) = bv[s];
        __syncthreads();
#pragma unroll
        for (int ks = 0; ks < 2; ++ks) {
            bf16x8 a[4], b[4];
#pragma unroll
            for (int i = 0; i < 4; ++i)
                a[i] = *(const bf16x8*)(As + (wm * 64 + i * 16 + n16) * LDP + ks * 32 + quad * 8);
#pragma unroll
            for (int i = 0; i < 4; ++i)
                b[i] = *(const bf16x8*)(Bs + (wn * 64 + i * 16 + n16) * LDP + ks * 32 + quad * 8);
#pragma unroll
            for (int i = 0; i < 4; ++i)
#pragma unroll
                for (int j = 0; j < 4; ++j)
                    acc[i][j] = __builtin_amdgcn_mfma_f32_16x16x32_bf16(a[i], b[j], acc[i][j], 0, 0, 0);
        }
    }
    // epilogue: fp32 output
#pragma unroll
    for (int j = 0; j < 4; ++j) {
        int o = obase + wn * 64 + j * 16 + n16;
        float bcv = bco[o];
#pragma unroll
        for (int i = 0; i < 4; ++i) {
            int prow = pbase + wm * 64 + i * 16 + quad * 4;
#pragma unroll
            for (int r = 0; r < 4; ++r)
                out[(size_t)(prow + r) * 384 + o] = acc[i][j][r] + bcv;
        }
    }
}

// ---------------------------------------------------------------- launch
extern "C" void kernel_launch(void* const* d_in, const int* in_sizes, int n_in,
                              void* d_out, int out_size, void* d_ws, size_t ws_size,
                              hipStream_t stream) {
    const float* x   = (const float*)d_in[0];
    const float* Wc  = (const float*)d_in[1];
    const float* bc  = (const float*)d_in[2];
    const float* Wo  = (const float*)d_in[3];
    const float* bo  = (const float*)d_in[4];
    const float* W1h = (const float*)d_in[5];
    const float* b1h = (const float*)d_in[6];
    const float* W2h = (const float*)d_in[7];
    const float* b2h = (const float*)d_in[8];
    const float* W1w = (const float*)d_in[9];
    const float* b1w = (const float*)d_in[10];
    const float* W2w = (const float*)d_in[11];
    const float* b2w = (const float*)d_in[12];
    float* out = (float*)d_out;

    char* ws = (char*)d_ws;
    size_t off = 0;
    auto alloc = [&](size_t bytes) {
        void* p = ws + off;
        off = (off + bytes + 255) & ~(size_t)255;
        return p;
    };
    bf16*  xb     = (bf16*)alloc((size_t)NPIX * 384 * 2);  // bf16 copy of x
    float* yh     = (float*)alloc((size_t)131072 * 4);     // [B][2][32][32]
    float* yw     = (float*)alloc((size_t)131072 * 4);
    bf16*  attn_h = (bf16*)alloc((size_t)2097152 * 2);     // [B][W][H][H]
    bf16*  attn_w = (bf16*)alloc((size_t)2097152 * 2);     // [B][H][W][W]
    bf16*  T      = (bf16*)alloc((size_t)NPIX * 384 * 2);  // Yh+Yw
    bf16*  Wfull  = (bf16*)alloc((size_t)384 * 768 * 2);   // [Wo | Wo@Wc]
    float* bco    = (float*)alloc((size_t)384 * 4);

    hipLaunchKernelGGL(k_prep_w, dim3(385), dim3(384), 0, stream, Wc, bc, Wo, bo, Wfull, bco);
    hipLaunchKernelGGL(k_proj, dim3(2048), dim3(256), 0, stream, x, xb, W1h, b1h, W1w, b1w, yh, yw);
    hipLaunchKernelGGL(k_attn, dim3(2048), dim3(64), 0, stream, yh, W2h, b2h, attn_h);
    hipLaunchKernelGGL(k_attn, dim3(2048), dim3(64), 0, stream, yw, W2w, b2w, attn_w);
    hipLaunchKernelGGL(k_mix, dim3(24, 64), dim3(256), 0, stream, xb, attn_h, attn_w, T);
    hipLaunchKernelGGL(k_gemm, dim3(1536), dim3(256), 0, stream, T, xb, Wfull, bco, out);
}

// Round 5
// 324.881 us; speedup vs baseline: 1.2706x; 1.1468x over previous
//
#include <hip/hip_runtime.h>
#include <hip/hip_bf16.h>
#include <cstdint>
#include <cstddef>

typedef __bf16 bf16;
typedef __attribute__((ext_vector_type(8))) __bf16 bf16x8;
typedef __attribute__((ext_vector_type(4))) float floatx4;

#define NPIX 65536   // B*H*W

__device__ inline void async_copy16(void* lds, const void* g) {
    __builtin_amdgcn_global_load_lds(
        (const __attribute__((address_space(1))) void*)g,
        (__attribute__((address_space(3))) void*)lds, 16, 0, 0);
}

// ---------------------------------------------------------------- K0: Wfull = [Wo | Wo@Wc] (bf16), bco = Wo@bc + bo (fp32)
__global__ void k_prep_w(const float* __restrict__ Wc, const float* __restrict__ bc,
                         const float* __restrict__ Wo, const float* __restrict__ bo,
                         bf16* __restrict__ Wfull, float* __restrict__ bco) {
    int blk = blockIdx.x;
    int t = threadIdx.x;          // 0..383
    if (blk < 384) {
        int o = blk;
        float acc = 0.f;
        for (int d = 0; d < 384; ++d)
            acc += Wo[o * 384 + d] * Wc[d * 384 + t];
        Wfull[(size_t)o * 768 + t]       = (bf16)Wo[o * 384 + t];
        Wfull[(size_t)o * 768 + 384 + t] = (bf16)acc;
    } else {
        int o = t;
        float acc = bo[o];
        for (int d = 0; d < 384; ++d)
            acc += Wo[o * 384 + d] * bc[d];
        bco[o] = acc;
    }
}

// ---------------------------------------------------------------- K1: convert + projections (E=2)
__global__ void k_proj(const float* __restrict__ xf, bf16* __restrict__ xb,
                       const float* __restrict__ W1h, const float* __restrict__ b1h,
                       const float* __restrict__ W1w, const float* __restrict__ b1w,
                       float* __restrict__ yh, float* __restrict__ yw) {
    int t  = threadIdx.x;
    int lg = t & 7;                 // lane within 8-lane pixel group
    int pg = t >> 3;                // pixel group in block (0..31)
    int p  = blockIdx.x * 32 + pg;  // pixel id
    int b = p >> 10, h = (p >> 5) & 31, w = p & 31;
    const float4* xp4 = (const float4*)(xf + (size_t)p * 384);
    float a0 = 0.f, a1 = 0.f, a2 = 0.f, a3 = 0.f;
#pragma unroll
    for (int j = 0; j < 6; ++j) {
        int c = j * 8 + lg;         // 8-element chunk 0..47
        float4 xa = xp4[c * 2], xcv = xp4[c * 2 + 1];
        bf16x8 v;
        v[0] = (bf16)xa.x; v[1] = (bf16)xa.y; v[2] = (bf16)xa.z; v[3] = (bf16)xa.w;
        v[4] = (bf16)xcv.x; v[5] = (bf16)xcv.y; v[6] = (bf16)xcv.z; v[7] = (bf16)xcv.w;
        *(bf16x8*)(xb + (size_t)p * 384 + c * 8) = v;
        const float4* h0 = (const float4*)(W1h + c * 8);
        const float4* h1 = (const float4*)(W1h + 384 + c * 8);
        const float4* w0 = (const float4*)(W1w + c * 8);
        const float4* w1 = (const float4*)(W1w + 384 + c * 8);
        float4 h0a = h0[0], h0b = h0[1], h1a = h1[0], h1b = h1[1];
        float4 w0a = w0[0], w0b = w0[1], w1a = w1[0], w1b = w1[1];
        a0 += xa.x*h0a.x + xa.y*h0a.y + xa.z*h0a.z + xa.w*h0a.w
            + xcv.x*h0b.x + xcv.y*h0b.y + xcv.z*h0b.z + xcv.w*h0b.w;
        a1 += xa.x*h1a.x + xa.y*h1a.y + xa.z*h1a.z + xa.w*h1a.w
            + xcv.x*h1b.x + xcv.y*h1b.y + xcv.z*h1b.z + xcv.w*h1b.w;
        a2 += xa.x*w0a.x + xa.y*w0a.y + xa.z*w0a.z + xa.w*w0a.w
            + xcv.x*w0b.x + xcv.y*w0b.y + xcv.z*w0b.z + xcv.w*w0b.w;
        a3 += xa.x*w1a.x + xa.y*w1a.y + xa.z*w1a.z + xa.w*w1a.w
            + xcv.x*w1b.x + xcv.y*w1b.y + xcv.z*w1b.z + xcv.w*w1b.w;
    }
#pragma unroll
    for (int m = 1; m < 8; m <<= 1) {
        a0 += __shfl_xor(a0, m, 64);
        a1 += __shfl_xor(a1, m, 64);
        a2 += __shfl_xor(a2, m, 64);
        a3 += __shfl_xor(a3, m, 64);
    }
    if (lg == 0) {
        yh[((b * 2 + 0) * 32 + h) * 32 + w] = a0 + b1h[0];
        yh[((b * 2 + 1) * 32 + h) * 32 + w] = a1 + b1h[1];
        yw[((b * 2 + 0) * 32 + w) * 32 + h] = a2 + b1w[0];
        yw[((b * 2 + 1) * 32 + w) * 32 + h] = a3 + b1w[1];
    }
}

// ---------------------------------------------------------------- K2: grouped mix + softmax -> attn[b][l][r1][r2] (bf16)
__global__ void k_attn(const float* __restrict__ yproj,
                       const float* __restrict__ W2, const float* __restrict__ b2,
                       bf16* __restrict__ attn) {
    int blk = blockIdx.x;                 // B*32
    int bi = blk >> 5, r1 = blk & 31;
    int g = r1 >> 2;
    int cb = g * 8;
    int e = cb >> 5, rb = cb & 31;        // 8 consecutive rows of plane e
    int lane = threadIdx.x;               // 64
    int l = lane & 31, half = lane >> 5;
    float yv[8];
    const float* ybase = yproj + (((bi * 2 + e) * 32 + rb) * 32 + l);
#pragma unroll
    for (int c = 0; c < 8; ++c) yv[c] = ybase[c * 32];
    float z[16];
#pragma unroll
    for (int jj = 0; jj < 16; ++jj) {
        int r2 = half * 16 + jj;
        int row = r1 * 32 + r2;
        const float4* wp = (const float4*)(W2 + (size_t)row * 8);
        float4 wa = wp[0], wb = wp[1];
        z[jj] = b2[row]
              + yv[0]*wa.x + yv[1]*wa.y + yv[2]*wa.z + yv[3]*wa.w
              + yv[4]*wb.x + yv[5]*wb.y + yv[6]*wb.z + yv[7]*wb.w;
    }
    float m = -1e30f;
#pragma unroll
    for (int jj = 0; jj < 16; ++jj) m = fmaxf(m, z[jj]);
    m = fmaxf(m, __shfl_xor(m, 32, 64));
    float s = 0.f;
#pragma unroll
    for (int jj = 0; jj < 16; ++jj) { z[jj] = __expf(z[jj] - m); s += z[jj]; }
    s += __shfl_xor(s, 32, 64);
    float inv = 1.f / s;
    bf16x8 o0, o1;
#pragma unroll
    for (int jj = 0; jj < 8; ++jj) o0[jj] = (bf16)(z[jj] * inv);
#pragma unroll
    for (int jj = 0; jj < 8; ++jj) o1[jj] = (bf16)(z[8 + jj] * inv);
    bf16x8* dst = (bf16x8*)(attn + ((((size_t)bi * 32 + l) * 32 + r1) * 32 + half * 16));
    dst[0] = o0;
    dst[1] = o1;
}

// ---------------------------------------------------------------- K3: fused Yh+Yw -> T (bf16)
// block = (image bi, 16-col d-slice c). Stage x-slice (32KB) into LDS via
// global_load_lds; phase1 Yh -> bf16 LDS; phase2 Yw + add -> T (one write).
// Grid swizzle: 4 c-siblings sharing a 128B line land on one XCD (n,n+8,..).
__global__ __launch_bounds__(256) void k_mix(const bf16* __restrict__ x,
                                             const bf16* __restrict__ attn_h,
                                             const bf16* __restrict__ attn_w,
                                             bf16* __restrict__ T) {
    __shared__ bf16 Xs[1024 * 16];      // [pixel][16 cols]  32 KB
    __shared__ bf16 Ts[1024 * 16];      // Yh park           32 KB
    int n = blockIdx.x;                 // 0..1535
    int a = n >> 5, r = n & 31;
    int q = a * 8 + (r & 7);            // 0..383
    int bi = q / 6, cq = q % 6;
    int c = cq * 4 + (r >> 3);          // 0..23
    int dbase = c * 16;
    int tid = threadIdx.x;
    int wv = tid >> 6, lane = tid & 63;
    int n16 = lane & 15, quad = lane >> 4;

    // ---- stage x[bi][:, dbase:dbase+16] -> Xs (lane-linear 16B chunks)
    const char* gbase = (const char*)(x + (size_t)bi * 1024 * 384 + dbase);
#pragma unroll
    for (int it = 0; it < 8; ++it) {
        int p0 = wv * 256 + it * 32;                 // 32 pixels per inst
        const char* g = gbase + (size_t)(p0 + (lane >> 1)) * 768 + (lane & 1) * 16;
        char* l = (char*)Xs + p0 * 32 + lane * 16;
        async_copy16(l, g);
    }
    __syncthreads();

    // ---- phase 1: Yh[h,w,d] = sum_j ah[w,h,j] x[j,w,d] -> Ts
#pragma unroll
    for (int wl = 0; wl < 8; ++wl) {
        int w = wv * 8 + wl;
        const bf16* ab = attn_h + ((size_t)(bi * 32 + w) * 32) * 32;
        bf16x8 af0 = *(const bf16x8*)(ab + n16 * 32 + quad * 8);
        bf16x8 af1 = *(const bf16x8*)(ab + (16 + n16) * 32 + quad * 8);
        bf16x8 bfrag;
#pragma unroll
        for (int i = 0; i < 8; ++i) {
            int j = quad * 8 + i;
            bfrag[i] = Xs[(j * 32 + w) * 16 + n16];
        }
        floatx4 c0 = {0.f, 0.f, 0.f, 0.f}, c1 = {0.f, 0.f, 0.f, 0.f};
        c0 = __builtin_amdgcn_mfma_f32_16x16x32_bf16(af0, bfrag, c0, 0, 0, 0);
        c1 = __builtin_amdgcn_mfma_f32_16x16x32_bf16(af1, bfrag, c1, 0, 0, 0);
#pragma unroll
        for (int rr = 0; rr < 4; ++rr) {
            int h0 = quad * 4 + rr;
            Ts[(h0 * 32 + w) * 16 + n16]        = (bf16)c0[rr];
            Ts[((16 + h0) * 32 + w) * 16 + n16] = (bf16)c1[rr];
        }
    }
    __syncthreads();

    // ---- phase 2: Yw[h,w,d] = sum_j aw[h,w,j] x[h,j,d]; T = Yh + Yw
#pragma unroll
    for (int hl = 0; hl < 8; ++hl) {
        int h = wv * 8 + hl;
        const bf16* ab = attn_w + ((size_t)(bi * 32 + h) * 32) * 32;
        bf16x8 af0 = *(const bf16x8*)(ab + n16 * 32 + quad * 8);
        bf16x8 af1 = *(const bf16x8*)(ab + (16 + n16) * 32 + quad * 8);
        bf16x8 bfrag;
#pragma unroll
        for (int i = 0; i < 8; ++i) {
            int j = quad * 8 + i;
            bfrag[i] = Xs[(h * 32 + j) * 16 + n16];
        }
        floatx4 c0 = {0.f, 0.f, 0.f, 0.f}, c1 = {0.f, 0.f, 0.f, 0.f};
        c0 = __builtin_amdgcn_mfma_f32_16x16x32_bf16(af0, bfrag, c0, 0, 0, 0);
        c1 = __builtin_amdgcn_mfma_f32_16x16x32_bf16(af1, bfrag, c1, 0, 0, 0);
        bf16* Tr = T + ((size_t)(bi * 32 + h) * 32) * 384 + dbase;
#pragma unroll
        for (int rr = 0; rr < 4; ++rr) {
            int w0 = quad * 4 + rr;
            Tr[(size_t)w0 * 384 + n16] =
                (bf16)(c0[rr] + (float)Ts[(h * 32 + w0) * 16 + n16]);
            Tr[(size_t)(16 + w0) * 384 + n16] =
                (bf16)(c1[rr] + (float)Ts[(h * 32 + 16 + w0) * 16 + n16]);
        }
    }
}

// ---------------------------------------------------------------- K5: out = [T|xb] @ Wfull^T + bco   (M=65536,N=384,K=768), out fp32
#define LDP 72
__global__ __launch_bounds__(256) void k_gemm(const bf16* __restrict__ T, const bf16* __restrict__ x,
                                              const bf16* __restrict__ Wfull, const float* __restrict__ bco,
                                              float* __restrict__ out) {
    __shared__ bf16 As[128 * LDP];
    __shared__ bf16 Bs[128 * LDP];
    int bx = blockIdx.x;               // 0..1535
    int gid = (bx & 7) * 192 + (bx >> 3);
    int nt = gid % 3, pt = gid / 3;
    int obase = nt * 128;
    int pbase = pt * 128;
    int tid = threadIdx.x;
    int wv = tid >> 6, lane = tid & 63;
    int wm = wv & 1, wn = wv >> 1;
    int n16 = lane & 15, quad = lane >> 4;
    int lrow = tid >> 3;           // 0..31
    int lchunk = tid & 7;          // 0..7
    floatx4 zero = {0.f, 0.f, 0.f, 0.f};
    floatx4 acc[4][4];
#pragma unroll
    for (int i = 0; i < 4; ++i)
#pragma unroll
        for (int j = 0; j < 4; ++j) acc[i][j] = zero;

    for (int kt = 0; kt < 12; ++kt) {
        const bf16* Asrc = (kt < 6) ? (T + (size_t)pbase * 384 + kt * 64)
                                    : (x + (size_t)pbase * 384 + (kt - 6) * 64);
        const bf16* Bsrc = Wfull + (size_t)obase * 768 + kt * 64;
        bf16x8 av[4], bv[4];
#pragma unroll
        for (int s = 0; s < 4; ++s)
            av[s] = *(const bf16x8*)(Asrc + (size_t)(s * 32 + lrow) * 384 + lchunk * 8);
#pragma unroll
        for (int s = 0; s < 4; ++s)
            bv[s] = *(const bf16x8*)(Bsrc + (size_t)(s * 32 + lrow) * 768 + lchunk * 8);
        __syncthreads();           // previous iteration's LDS reads done
#pragma unroll
        for (int s = 0; s < 4; ++s)
            *(bf16x8*)(As + (s * 32 + lrow) * LDP + lchunk * 8) = av[s];
#pragma unroll
        for (int s = 0; s < 4; ++s)
            *(bf16x8*)(Bs + (s * 32 + lrow) * LDP + lchunk * 8) = bv[s];
        __syncthreads();
#pragma unroll
        for (int ks = 0; ks < 2; ++ks) {
            bf16x8 a[4], b[4];
#pragma unroll
            for (int i = 0; i < 4; ++i)
                a[i] = *(const bf16x8*)(As + (wm * 64 + i * 16 + n16) * LDP + ks * 32 + quad * 8);
#pragma unroll
            for (int i = 0; i < 4; ++i)
                b[i] = *(const bf16x8*)(Bs + (wn * 64 + i * 16 + n16) * LDP + ks * 32 + quad * 8);
#pragma unroll
            for (int i = 0; i < 4; ++i)
#pragma unroll
                for (int j = 0; j < 4; ++j)
                    acc[i][j] = __builtin_amdgcn_mfma_f32_16x16x32_bf16(a[i], b[j], acc[i][j], 0, 0, 0);
        }
    }
    // epilogue: fp32 output
#pragma unroll
    for (int j = 0; j < 4; ++j) {
        int o = obase + wn * 64 + j * 16 + n16;
        float bcv = bco[o];
#pragma unroll
        for (int i = 0; i < 4; ++i) {
            int prow = pbase + wm * 64 + i * 16 + quad * 4;
#pragma unroll
            for (int r = 0; r < 4; ++r)
                out[(size_t)(prow + r) * 384 + o] = acc[i][j][r] + bcv;
        }
    }
}

// ---------------------------------------------------------------- launch
extern "C" void kernel_launch(void* const* d_in, const int* in_sizes, int n_in,
                              void* d_out, int out_size, void* d_ws, size_t ws_size,
                              hipStream_t stream) {
    const float* x   = (const float*)d_in[0];
    const float* Wc  = (const float*)d_in[1];
    const float* bc  = (const float*)d_in[2];
    const float* Wo  = (const float*)d_in[3];
    const float* bo  = (const float*)d_in[4];
    const float* W1h = (const float*)d_in[5];
    const float* b1h = (const float*)d_in[6];
    const float* W2h = (const float*)d_in[7];
    const float* b2h = (const float*)d_in[8];
    const float* W1w = (const float*)d_in[9];
    const float* b1w = (const float*)d_in[10];
    const float* W2w = (const float*)d_in[11];
    const float* b2w = (const float*)d_in[12];
    float* out = (float*)d_out;

    char* ws = (char*)d_ws;
    size_t off = 0;
    auto alloc = [&](size_t bytes) {
        void* p = ws + off;
        off = (off + bytes + 255) & ~(size_t)255;
        return p;
    };
    bf16*  xb     = (bf16*)alloc((size_t)NPIX * 384 * 2);  // bf16 copy of x
    float* yh     = (float*)alloc((size_t)131072 * 4);     // [B][2][32][32]
    float* yw     = (float*)alloc((size_t)131072 * 4);
    bf16*  attn_h = (bf16*)alloc((size_t)2097152 * 2);     // [B][W][H][H]
    bf16*  attn_w = (bf16*)alloc((size_t)2097152 * 2);     // [B][H][W][W]
    bf16*  T      = (bf16*)alloc((size_t)NPIX * 384 * 2);  // Yh+Yw
    bf16*  Wfull  = (bf16*)alloc((size_t)384 * 768 * 2);   // [Wo | Wo@Wc]
    float* bco    = (float*)alloc((size_t)384 * 4);

    hipLaunchKernelGGL(k_prep_w, dim3(385), dim3(384), 0, stream, Wc, bc, Wo, bo, Wfull, bco);
    hipLaunchKernelGGL(k_proj, dim3(2048), dim3(256), 0, stream, x, xb, W1h, b1h, W1w, b1w, yh, yw);
    hipLaunchKernelGGL(k_attn, dim3(2048), dim3(64), 0, stream, yh, W2h, b2h, attn_h);
    hipLaunchKernelGGL(k_attn, dim3(2048), dim3(64), 0, stream, yw, W2w, b2w, attn_w);
    hipLaunchKernelGGL(k_mix, dim3(1536), dim3(256), 0, stream, xb, attn_h, attn_w, T);
    hipLaunchKernelGGL(k_gemm, dim3(1536), dim3(256), 0, stream, T, xb, Wfull, bco, out);
}